// Round 2
// baseline (566.027 us; speedup 1.0000x reference)
//
#include <hip/hip_runtime.h>

// out[row, :] = 1 / where(d[idx,:]==0, BIG, d[idx,:])
// idx = venueid2coor[inputs_poi[row]], row in [0, B*S)
// N_POI = 10000 -> 2500 float4 per row, 40000-byte row stride (16B aligned).

typedef float v4f __attribute__((ext_vector_type(4)));  // clang vector: legal for nontemporal builtins

#define ROW_F4 2500
#define BIGF 9999999.99f  // rounds to 1e7f in fp32, matching the jnp.float32 ref

__global__ __launch_bounds__(256) void attn_loc_distance_kernel(
    const int* __restrict__ v2c,        // [V] venue id -> matrix row
    const int* __restrict__ poi,        // [B*S] venue ids
    const v4f* __restrict__ dmat,       // [N_POI, ROW_F4]
    v4f* __restrict__ out) {            // [B*S, ROW_F4]
    const int row = blockIdx.x;
    // wave-uniform double indirection (scalar loads, broadcast to all lanes)
    const int idx = v2c[poi[row]];
    const v4f* __restrict__ src = dmat + (size_t)idx * ROW_F4;
    v4f* __restrict__ dst = out + (size_t)row * ROW_F4;

    for (int i = threadIdx.x; i < ROW_F4; i += 256) {
        v4f x = src[i];
        v4f y;
        y.x = 1.0f / ((x.x == 0.0f) ? BIGF : x.x);
        y.y = 1.0f / ((x.y == 0.0f) ? BIGF : x.y);
        y.z = 1.0f / ((x.z == 0.0f) ? BIGF : x.z);
        y.w = 1.0f / ((x.w == 0.0f) ? BIGF : x.w);
        // write-once 256 MB stream: keep it out of L2/L3 so the gathered
        // distance-matrix rows (which have ~1.35x reuse) stay cached
        __builtin_nontemporal_store(y, dst + i);
    }
}

extern "C" void kernel_launch(void* const* d_in, const int* in_sizes, int n_in,
                              void* d_out, int out_size, void* d_ws, size_t ws_size,
                              hipStream_t stream) {
    const int*   v2c  = (const int*)d_in[0];     // venueid2coor (int32 on device)
    const int*   poi  = (const int*)d_in[1];     // inputs_poi   (int32 on device)
    const float* dmat = (const float*)d_in[2];   // poi_distance_matrix
    float*       out  = (float*)d_out;

    const int rows = in_sizes[1];                // B*S = 6400
    attn_loc_distance_kernel<<<rows, 256, 0, stream>>>(
        v2c, poi, (const v4f*)dmat, (v4f*)out);
}